// Round 1
// 924.472 us; speedup vs baseline: 1.1283x; 1.1283x over previous
//
#include <hip/hip_runtime.h>

typedef __bf16 bf16x8 __attribute__((ext_vector_type(8)));
typedef __bf16 bf16x4 __attribute__((ext_vector_type(4)));
typedef __bf16 bf16x2 __attribute__((ext_vector_type(2)));
typedef float  f32x4  __attribute__((ext_vector_type(4)));

#define NG 5000
#define NU 100000
#define NI 20000
#define H  128
#define EUG 300000
#define EUI 600000
#define EGI 200000
#define ETOT (EUG + EGI + EUI + EUI)   // 1,700,000
#define NN  (2 * NG + NU + NI)         // 130,000 concatenated nodes

// ---------------- workspace layout (bytes) ----------------
#define B_EMBU  0UL            // NU*H bf16
#define B_EMBI  25600000UL     // NI*H bf16
#define B_AGGU  30720000UL     // NU*H bf16  (i->u mean of embI_t, then hu1 in-place)
#define B_AGGI  56320000UL     // NI*H bf16  (u->i mean, then hi1 in-place)
#define B_AGGG1 61440000UL     // NG*H bf16  (u->g mean L1)
#define B_AGGG2 62720000UL     // NG*H bf16  (i->g mean L1)
#define B_HG1   64000000UL     // NG*H bf16
#define B_GU    65280000UL     // NG*H bf16 (L2 u->g of hu1)
#define B_GI    66560000UL     // NG*H bf16 (L2 i->g of hi1)
#define B_REP   67840000UL     // NG*H bf16 (relu(og2))
#define B_BC    69120000UL     // 4*128 f32
#define B_PWT   69122048UL     // NI*H bf16
#define B_WT    74242048UL     // 9*16384 bf16
#define B_CNT   74536960UL     // NN int
#define B_OFFS  75056960UL     // NN+1 int (+pad)
#define B_CUR   75576976UL     // NN int
#define B_EIDX  76096976UL     // ETOT int -> end 82,896,976
#define B_EIT   82897024UL     // NI*H bf16 (embI @ W1l[3]) -> end 88,017,024

// chunksum/chunkbase (64 ints) overlap B_AGGU: dead until seg phase. safe.

#define SCAN_CHUNK 2048
#define NCHUNK 64

// phase1 block ranges
#define NB_PREP 10
#define NB_TP   626      // 313 x 2
#define NB_CVU  12500    // NU*32/256
#define NB_CVI  2500     // NI*32/256
#define NB_HIST 6641     // ceil(ETOT/256)
#define NB_P1   (NB_PREP + NB_TP + NB_CVU + NB_CVI + NB_HIST)

// gemm1 block ranges
#define NBU 782
#define NBI 157
#define NBG 40

// XOR-swizzled LDS index (8-elem bf16 chunks)
__device__ __forceinline__ int swz(int row, int k) {
  return ((((k >> 3) ^ (row & 15)) << 3) | (k & 7));
}
// fp32 epilogue swizzle
__device__ __forceinline__ int cswz(int row, int col) {
  return col ^ (((row >> 2) & 1) << 4);
}

// ---------------- device bodies ----------------
__device__ void prep_dev(const float* __restrict__ W1l, const float* __restrict__ W1r,
                         const float* __restrict__ W2l, const float* __restrict__ W2r,
                         const float* __restrict__ b1, const float* __restrict__ b2,
                         __bf16* __restrict__ WT, float* __restrict__ bc, int b, int tid) {
  if (b < 9) {
    const float* Wa; const float* Wb = nullptr;
    switch (b) {
      case 0: Wa = W1r + 1 * 16384; Wb = W1r + 3 * 16384; break;  // hu1: emb term
      case 1: Wa = W1l + 3 * 16384; break;                        // embI_t projection
      case 2: Wa = W1l + 2 * 16384; break;                        // hi1: agg term
      case 3: Wa = W1r + 2 * 16384; Wb = W1r + 4 * 16384; break;  // hi1: emb term
      case 4: Wa = W1l + 0 * 16384; break;                        // hg1: u->g
      case 5: Wa = W1l + 5 * 16384; break;                        // hg1: i->g
      case 6: Wa = W2r + 0 * 16384; Wb = W2r + 5 * 16384; break;  // og2: hg1 term
      case 7: Wa = W2l + 0 * 16384; break;                        // og2: gU term
      default: Wa = W2l + 5 * 16384; break;                       // og2: gI term
    }
    __bf16* dst = WT + b * 16384;
    for (int idx = tid; idx < 16384; idx += 256) {
      int k = idx >> 7, c = idx & 127;
      float v = Wa[idx];
      if (Wb) v += Wb[idx];
      dst[c * 128 + k] = (__bf16)v;
    }
  } else {
    if (tid < 128) {
      bc[tid]       = b1[128 + tid]     + b1[3 * 128 + tid];  // user
      bc[128 + tid] = b1[2 * 128 + tid] + b1[4 * 128 + tid];  // item
      bc[256 + tid] = b1[tid]           + b1[5 * 128 + tid];  // group L1
      bc[384 + tid] = b2[tid]           + b2[5 * 128 + tid];  // group L2
    }
  }
}

__device__ void transpose_dev(const float* __restrict__ pw, __bf16* __restrict__ pwt,
                              int bx, int by, int tid, float (*t)[65]) {
  int i0 = bx * 64, k0 = by * 64;
  for (int idx = tid; idx < 64 * 16; idx += 256) {
    int kk = idx >> 4, c4 = (idx & 15) << 2;
    int ib = i0 + c4;
    float x0 = 0.f, x1 = 0.f, x2 = 0.f, x3 = 0.f;
    const float* src = pw + (size_t)(k0 + kk) * NI + ib;
    if (ib + 3 < NI) {
      const float4 v = *(const float4*)src;
      x0 = v.x; x1 = v.y; x2 = v.z; x3 = v.w;
    } else {
      if (ib + 0 < NI) x0 = src[0];
      if (ib + 1 < NI) x1 = src[1];
      if (ib + 2 < NI) x2 = src[2];
      if (ib + 3 < NI) x3 = src[3];
    }
    t[kk][c4 + 0] = x0; t[kk][c4 + 1] = x1; t[kk][c4 + 2] = x2; t[kk][c4 + 3] = x3;
  }
  __syncthreads();
  for (int idx = tid; idx < 64 * 16; idx += 256) {
    int ii = idx >> 4, k4 = (idx & 15) << 2;
    int gi = i0 + ii;
    if (gi < NI) {
      bf16x4 o;
      o[0] = (__bf16)t[k4 + 0][ii]; o[1] = (__bf16)t[k4 + 1][ii];
      o[2] = (__bf16)t[k4 + 2][ii]; o[3] = (__bf16)t[k4 + 3][ii];
      *(bf16x4*)(pwt + (size_t)gi * 128 + k0 + k4) = o;
    }
  }
}

__device__ void cvt_dev(const float* __restrict__ src, __bf16* __restrict__ dst,
                        int b, int tid, int n4) {
  int i = b * 256 + tid;
  if (i < n4) {
    float4 v = ((const float4*)src)[i];
    bf16x4 o;
    o[0] = (__bf16)v.x; o[1] = (__bf16)v.y; o[2] = (__bf16)v.z; o[3] = (__bf16)v.w;
    ((bf16x4*)dst)[i] = o;
  }
}

__device__ void hist_dev(const int* __restrict__ ug_dst, const int* __restrict__ gi_src,
                         const int* __restrict__ ui_src, const int* __restrict__ ui_dst,
                         int* __restrict__ cnt, int b, int tid) {
  int i = b * 256 + tid;
  int key, base;
  if (i < EUG)                       { key = ug_dst[i];                   base = 0; }
  else if (i < EUG + EGI)            { key = gi_src[i - EUG];             base = NG; }
  else if (i < EUG + EGI + EUI)      { key = ui_src[i - EUG - EGI];       base = 2 * NG; }
  else if (i < ETOT)                 { key = ui_dst[i - EUG - EGI - EUI]; base = 2 * NG + NU; }
  else return;
  atomicAdd(&cnt[base + key], 1);
}

// ---------------- fused GEMM core ----------------
// C = act(sum_t A_t @ B_t + bias + Dadd). A:[N,128] bf16 rm, B:[NC,128] bf16 [col][k].
__device__ void gemm_core(const __bf16* __restrict__ A0, const __bf16* __restrict__ B0,
                          const __bf16* __restrict__ A1, const __bf16* __restrict__ B1,
                          const __bf16* __restrict__ A2, const __bf16* __restrict__ B2,
                          const __bf16* __restrict__ Dadd, const float* __restrict__ bias,
                          float* __restrict__ Cf, __bf16* __restrict__ Cb,
                          int N, int NC, int nterms, int relu,
                          int rowblk, int colblk, char* smem_raw) {
  __bf16* sA = (__bf16*)smem_raw;
  __bf16* sB = sA + 128 * 128;
  float* sC = (float*)smem_raw;
  int tid = threadIdx.x;
  int rowbase = rowblk * 128, colbase = colblk * 128;
  int wid = tid >> 6, lane = tid & 63;
  int qrow = (wid >> 1) << 6, qcol = (wid & 1) << 6;
  int lrow = lane & 15, quad = lane >> 4;

  f32x4 acc[4][4];
#pragma unroll
  for (int mi = 0; mi < 4; ++mi)
#pragma unroll
    for (int ni = 0; ni < 4; ++ni) acc[mi][ni] = (f32x4){0.f, 0.f, 0.f, 0.f};

  const __bf16* As[3] = {A0, A1, A2};
  const __bf16* Bs[3] = {B0, B1, B2};

  for (int t = 0; t < nterms; ++t) {
    __syncthreads();
    const __bf16* A = As[t];
    for (int idx = tid; idx < 2048; idx += 256) {
      int row = idx >> 4, c8 = (idx & 15) << 3;
      int grow = rowbase + row;
      bf16x8 v;
      if (grow < N) v = *(const bf16x8*)(A + (size_t)grow * 128 + c8);
      else { for (int u = 0; u < 8; ++u) v[u] = (__bf16)0.f; }
      *(bf16x8*)&sA[row * 128 + swz(row, c8)] = v;
    }
    const __bf16* B = Bs[t];
    for (int idx = tid; idx < 2048; idx += 256) {
      int n = idx >> 4, c8 = (idx & 15) << 3;
      int gcol = colbase + n;
      bf16x8 v;
      if (gcol < NC) v = *(const bf16x8*)(B + (size_t)gcol * 128 + c8);
      else { for (int u = 0; u < 8; ++u) v[u] = (__bf16)0.f; }
      *(bf16x8*)&sB[n * 128 + swz(n, c8)] = v;
    }
    __syncthreads();
#pragma unroll
    for (int kb = 0; kb < 4; ++kb) {
      int k0 = kb * 32 + quad * 8;
      bf16x8 af[4], bfr[4];
#pragma unroll
      for (int mi = 0; mi < 4; ++mi) {
        int r = qrow + mi * 16 + lrow;
        af[mi] = *(const bf16x8*)&sA[r * 128 + swz(r, k0)];
      }
#pragma unroll
      for (int ni = 0; ni < 4; ++ni) {
        int r = qcol + ni * 16 + lrow;
        bfr[ni] = *(const bf16x8*)&sB[r * 128 + swz(r, k0)];
      }
#pragma unroll
      for (int mi = 0; mi < 4; ++mi)
#pragma unroll
        for (int ni = 0; ni < 4; ++ni)
          acc[mi][ni] = __builtin_amdgcn_mfma_f32_16x16x32_bf16(af[mi], bfr[ni], acc[mi][ni], 0, 0, 0);
    }
  }

  __syncthreads();
#pragma unroll
  for (int mi = 0; mi < 4; ++mi) {
#pragma unroll
    for (int ni = 0; ni < 4; ++ni) {
      int col = qcol + ni * 16 + lrow;
#pragma unroll
      for (int r = 0; r < 4; ++r) {
        int row = qrow + mi * 16 + quad * 4 + r;
        sC[row * 128 + cswz(row, col)] = acc[mi][ni][r];
      }
    }
  }
  __syncthreads();
  for (int idx = tid; idx < 4096; idx += 256) {
    int row = idx >> 5, c4 = (idx & 31) << 2;
    int grow = rowbase + row, gcol = colbase + c4;
    if (grow >= N) continue;
    f32x4 v = *(const f32x4*)&sC[row * 128 + cswz(row, c4)];
    if (gcol + 3 < NC) {
      if (bias) {
        f32x4 bv = *(const f32x4*)&bias[gcol];
        v += bv;
      }
      if (Dadd) {
        bf16x4 dv = *(const bf16x4*)(Dadd + (size_t)grow * 128 + gcol);
        v[0] += (float)dv[0]; v[1] += (float)dv[1];
        v[2] += (float)dv[2]; v[3] += (float)dv[3];
      }
      if (relu) {
#pragma unroll
        for (int u = 0; u < 4; ++u) v[u] = fmaxf(v[u], 0.f);
      }
      if (Cb) {
        bf16x4 o;
        o[0] = (__bf16)v[0]; o[1] = (__bf16)v[1]; o[2] = (__bf16)v[2]; o[3] = (__bf16)v[3];
        *(bf16x4*)(Cb + (size_t)grow * NC + gcol) = o;
      } else {
        __builtin_nontemporal_store(v, (f32x4*)(Cf + (size_t)grow * NC + gcol));
      }
    } else {
#pragma unroll
      for (int u = 0; u < 4; ++u) {
        if (gcol + u < NC) {
          float x = v[u] + (bias ? bias[gcol + u] : 0.f);
          if (Dadd) x += (float)Dadd[(size_t)grow * 128 + gcol + u];
          if (relu) x = fmaxf(x, 0.f);
          if (Cb) Cb[(size_t)grow * NC + gcol + u] = (__bf16)x;
          else    Cf[(size_t)grow * NC + gcol + u] = x;
        }
      }
    }
  }
}

// ---------------- segment-mean body (one wave = one node) ----------------
__device__ void seg_dev(const __bf16* __restrict__ feat, const int* __restrict__ offs,
                        const int* __restrict__ eidx, __bf16* __restrict__ out,
                        int node, int orow, int lane) {
  int s = offs[node], e = offs[node + 1];
  float a0 = 0.f, a1 = 0.f;
  int j = s;
  for (; j + 4 <= e; j += 4) {
    int i0 = eidx[j], i1 = eidx[j + 1], i2 = eidx[j + 2], i3 = eidx[j + 3];
    bf16x2 v0 = *(const bf16x2*)(feat + (size_t)i0 * 128 + lane * 2);
    bf16x2 v1 = *(const bf16x2*)(feat + (size_t)i1 * 128 + lane * 2);
    bf16x2 v2 = *(const bf16x2*)(feat + (size_t)i2 * 128 + lane * 2);
    bf16x2 v3 = *(const bf16x2*)(feat + (size_t)i3 * 128 + lane * 2);
    a0 += (float)v0[0] + (float)v1[0] + (float)v2[0] + (float)v3[0];
    a1 += (float)v0[1] + (float)v1[1] + (float)v2[1] + (float)v3[1];
  }
  if (j + 2 <= e) {
    int i0 = eidx[j], i1 = eidx[j + 1];
    bf16x2 v0 = *(const bf16x2*)(feat + (size_t)i0 * 128 + lane * 2);
    bf16x2 v1 = *(const bf16x2*)(feat + (size_t)i1 * 128 + lane * 2);
    a0 += (float)v0[0] + (float)v1[0];
    a1 += (float)v0[1] + (float)v1[1];
    j += 2;
  }
  if (j < e) {
    int i0 = eidx[j];
    bf16x2 v0 = *(const bf16x2*)(feat + (size_t)i0 * 128 + lane * 2);
    a0 += (float)v0[0]; a1 += (float)v0[1];
  }
  float inv = (e > s) ? (1.f / (float)(e - s)) : 0.f;
  bf16x2 o;
  o[0] = (__bf16)(a0 * inv); o[1] = (__bf16)(a1 * inv);
  *(bf16x2*)(out + (size_t)orow * 128 + lane * 2) = o;
}

// ---------------- kernels ----------------
__global__ __launch_bounds__(256)
void phase1(const float* __restrict__ W1l, const float* __restrict__ W1r,
            const float* __restrict__ W2l, const float* __restrict__ W2r,
            const float* __restrict__ b1, const float* __restrict__ b2,
            const float* __restrict__ predW,
            const float* __restrict__ emb_user, const float* __restrict__ emb_item,
            const int* __restrict__ ug_dst, const int* __restrict__ gi_src,
            const int* __restrict__ ui_src, const int* __restrict__ ui_dst,
            char* __restrict__ ws) {
  __shared__ float tbuf[64][65];
  __bf16* WT = (__bf16*)(ws + B_WT);
  float* bc  = (float*)(ws + B_BC);
  __bf16* pwt = (__bf16*)(ws + B_PWT);
  __bf16* embU = (__bf16*)(ws + B_EMBU);
  __bf16* embI = (__bf16*)(ws + B_EMBI);
  int* cnt = (int*)(ws + B_CNT);
  int b = blockIdx.x, tid = threadIdx.x;
  if (b < NB_PREP) { prep_dev(W1l, W1r, W2l, W2r, b1, b2, WT, bc, b, tid); return; }
  b -= NB_PREP;
  if (b < NB_TP) { transpose_dev(predW, pwt, b % 313, b / 313, tid, tbuf); return; }
  b -= NB_TP;
  if (b < NB_CVU) { cvt_dev(emb_user, embU, b, tid, NU * 32); return; }
  b -= NB_CVU;
  if (b < NB_CVI) { cvt_dev(emb_item, embI, b, tid, NI * 32); return; }
  b -= NB_CVI;
  hist_dev(ug_dst, gi_src, ui_src, ui_dst, cnt, b, tid);
}

__global__ __launch_bounds__(256)
void scan_k1(const int* __restrict__ cnt, int* __restrict__ chunksum) {
  __shared__ int ws4[4];
  int b = blockIdx.x, tid = threadIdx.x, lane = tid & 63, w = tid >> 6;
  int base = b * SCAN_CHUNK + tid * 8;
  int s = 0;
#pragma unroll
  for (int j = 0; j < 8; ++j) { int i = base + j; if (i < NN) s += cnt[i]; }
#pragma unroll
  for (int d = 1; d < 64; d <<= 1) s += __shfl_xor(s, d, 64);
  if (lane == 0) ws4[w] = s;
  __syncthreads();
  if (tid == 0) chunksum[b] = ws4[0] + ws4[1] + ws4[2] + ws4[3];
}

// scan_k2+k3 fused (blocks 0..63) + embI_t projection GEMM (blocks 64..220)
__global__ __launch_bounds__(256)
void scan2_gemm0(char* __restrict__ ws) {
  __shared__ char smem[65536];
  int b = blockIdx.x, tid = threadIdx.x;
  if (b < NCHUNK) {
    int* shi = (int*)smem;  // shi[0..3]=wave sums, shi[4]=chunkbase for this block
    const int* cnt = (const int*)(ws + B_CNT);
    const int* chunksum = (const int*)(ws + B_AGGU);
    int* offs = (int*)(ws + B_OFFS);
    int* cur  = (int*)(ws + B_CUR);
    int lane = tid & 63, w = tid >> 6;
    if (w == 0) {
      int v = chunksum[lane];
      int incl = v;
#pragma unroll
      for (int d = 1; d < 64; d <<= 1) { int t = __shfl_up(incl, d, 64); if (lane >= d) incl += t; }
      if (lane == b) shi[4] = incl - v;
    }
    int base = b * SCAN_CHUNK + tid * 8;
    int x[8]; int s = 0;
#pragma unroll
    for (int j = 0; j < 8; ++j) { int i = base + j; x[j] = (i < NN) ? cnt[i] : 0; s += x[j]; }
    int incl = s;
#pragma unroll
    for (int d = 1; d < 64; d <<= 1) { int t = __shfl_up(incl, d, 64); if (lane >= d) incl += t; }
    if (lane == 63) shi[w] = incl;
    __syncthreads();
    int wpre = 0;
    for (int ww = 0; ww < w; ++ww) wpre += shi[ww];
    int excl = shi[4] + wpre + incl - s;
#pragma unroll
    for (int j = 0; j < 8; ++j) {
      int i = base + j;
      if (i < NN) { offs[i] = excl; cur[i] = excl; }
      excl += x[j];
      if (i == NN - 1) offs[NN] = excl;
    }
  } else {
    // embI_t = embI @ W1l[3]  (no bias, no relu)
    const __bf16* embI = (const __bf16*)(ws + B_EMBI);
    const __bf16* WT   = (const __bf16*)(ws + B_WT);
    __bf16* eit = (__bf16*)(ws + B_EIT);
    gemm_core(embI, WT + 1 * 16384, nullptr, nullptr, nullptr, nullptr,
              nullptr, nullptr, nullptr, eit, NI, 128, 1, 0, b - NCHUNK, 0, smem);
  }
}

__global__ __launch_bounds__(256)
void fill_all(const int* __restrict__ ug_src, const int* __restrict__ ug_dst,
              const int* __restrict__ gi_src, const int* __restrict__ gi_dst,
              const int* __restrict__ ui_src, const int* __restrict__ ui_dst,
              int* __restrict__ cur, int* __restrict__ eidx) {
  int i = blockIdx.x * 256 + threadIdx.x;
  int key, base, payload;
  if (i < EUG)                  { key = ug_dst[i];       base = 0;            payload = ug_src[i]; }
  else if (i < EUG + EGI)       { int j = i - EUG;       key = gi_src[j]; base = NG;          payload = gi_dst[j]; }
  else if (i < EUG + EGI + EUI) { int j = i - EUG - EGI; key = ui_src[j]; base = 2 * NG;      payload = ui_dst[j]; }
  else if (i < ETOT)            { int j = i - EUG - EGI - EUI; key = ui_dst[j]; base = 2 * NG + NU; payload = ui_src[j]; }
  else return;
  int pos = atomicAdd(&cur[base + key], 1);
  eidx[pos] = payload;
}

// all four L1 aggregations in one launch over the concatenated node space
__global__ __launch_bounds__(256)
void seg1(char* __restrict__ ws) {
  int w = threadIdx.x >> 6, lane = threadIdx.x & 63;
  int node = blockIdx.x * 4 + w;
  if (node >= NN) return;
  const int* offs = (const int*)(ws + B_OFFS);
  const int* eidx = (const int*)(ws + B_EIDX);
  const __bf16* feat; __bf16* out; int orow;
  if (node < NG)               { feat = (const __bf16*)(ws + B_EMBU); out = (__bf16*)(ws + B_AGGG1); orow = node; }
  else if (node < 2 * NG)      { feat = (const __bf16*)(ws + B_EMBI); out = (__bf16*)(ws + B_AGGG2); orow = node - NG; }
  else if (node < 2 * NG + NU) { feat = (const __bf16*)(ws + B_EIT);  out = (__bf16*)(ws + B_AGGU);  orow = node - 2 * NG; }
  else                         { feat = (const __bf16*)(ws + B_EMBU); out = (__bf16*)(ws + B_AGGI);  orow = node - 2 * NG - NU; }
  seg_dev(feat, offs, eidx, out, node, orow, lane);
}

// hu1 + hi1 + hg1 in one launch
__global__ __launch_bounds__(256)
void gemm1(char* __restrict__ ws) {
  __shared__ char smem[65536];
  const __bf16* WT = (const __bf16*)(ws + B_WT);
  const float* bc  = (const float*)(ws + B_BC);
  int b = blockIdx.x;
  if (b < NBU) {
    // hu1 = relu(embU @ (W1r1+W1r3) + aggU_t + bc0); in-place into aggU
    __bf16* aggU = (__bf16*)(ws + B_AGGU);
    gemm_core((const __bf16*)(ws + B_EMBU), WT + 0 * 16384,
              nullptr, nullptr, nullptr, nullptr,
              aggU, bc + 0, nullptr, aggU, NU, 128, 1, 1, b, 0, smem);
  } else if (b < NBU + NBI) {
    __bf16* aggI = (__bf16*)(ws + B_AGGI);
    gemm_core(aggI, WT + 2 * 16384,
              (const __bf16*)(ws + B_EMBI), WT + 3 * 16384, nullptr, nullptr,
              nullptr, bc + 128, nullptr, aggI, NI, 128, 2, 1, b - NBU, 0, smem);
  } else {
    gemm_core((const __bf16*)(ws + B_AGGG1), WT + 4 * 16384,
              (const __bf16*)(ws + B_AGGG2), WT + 5 * 16384, nullptr, nullptr,
              nullptr, bc + 256, nullptr, (__bf16*)(ws + B_HG1), NG, 128, 2, 1,
              b - NBU - NBI, 0, smem);
  }
}

// both L2 group aggregations in one launch
__global__ __launch_bounds__(256)
void seg2(char* __restrict__ ws) {
  int w = threadIdx.x >> 6, lane = threadIdx.x & 63;
  int node = blockIdx.x * 4 + w;
  if (node >= 2 * NG) return;
  const int* offs = (const int*)(ws + B_OFFS);
  const int* eidx = (const int*)(ws + B_EIDX);
  const __bf16* feat; __bf16* out; int orow;
  if (node < NG) { feat = (const __bf16*)(ws + B_AGGU); out = (__bf16*)(ws + B_GU); orow = node; }
  else           { feat = (const __bf16*)(ws + B_AGGI); out = (__bf16*)(ws + B_GI); orow = node - NG; }
  seg_dev(feat, offs, eidx, out, node, orow, lane);
}

__global__ __launch_bounds__(256)
void gemm2(char* __restrict__ ws) {
  __shared__ char smem[65536];
  const __bf16* WT = (const __bf16*)(ws + B_WT);
  const float* bc  = (const float*)(ws + B_BC);
  gemm_core((const __bf16*)(ws + B_GU),  WT + 7 * 16384,
            (const __bf16*)(ws + B_HG1), WT + 6 * 16384,
            (const __bf16*)(ws + B_GI),  WT + 8 * 16384,
            nullptr, bc + 384, nullptr, (__bf16*)(ws + B_REP), NG, 128, 3, 1,
            blockIdx.x, 0, smem);
}

__global__ __launch_bounds__(256)
void gemmF(char* __restrict__ ws, const float* __restrict__ predb, float* __restrict__ out) {
  __shared__ char smem[65536];
  gemm_core((const __bf16*)(ws + B_REP), (const __bf16*)(ws + B_PWT),
            nullptr, nullptr, nullptr, nullptr,
            nullptr, predb, out, nullptr, NG, NI, 1, 0,
            blockIdx.x, blockIdx.y, smem);
}

// ---------------- launch ----------------
extern "C" void kernel_launch(void* const* d_in, const int* in_sizes, int n_in,
                              void* d_out, int out_size, void* d_ws, size_t ws_size,
                              hipStream_t stream) {
  const float* emb_user = (const float*)d_in[4];
  const float* emb_item = (const float*)d_in[5];
  const float* W1l = (const float*)d_in[6];
  const float* W1r = (const float*)d_in[7];
  const float* b1  = (const float*)d_in[8];
  const float* W2l = (const float*)d_in[9];
  const float* W2r = (const float*)d_in[10];
  const float* b2  = (const float*)d_in[11];
  const float* predW = (const float*)d_in[12];
  const float* predb = (const float*)d_in[13];
  const int* ug_src = (const int*)d_in[14];
  const int* ug_dst = (const int*)d_in[15];
  const int* ui_src = (const int*)d_in[16];
  const int* ui_dst = (const int*)d_in[17];
  const int* gi_src = (const int*)d_in[18];
  const int* gi_dst = (const int*)d_in[19];

  char* ws = (char*)d_ws;
  int* cnt  = (int*)(ws + B_CNT);
  int* cur  = (int*)(ws + B_CUR);
  int* eidx = (int*)(ws + B_EIDX);
  int* chunksum = (int*)(ws + B_AGGU);   // scratch overlap, dead until seg1

  hipMemsetAsync(cnt, 0, NN * sizeof(int), stream);

  phase1<<<NB_P1, 256, 0, stream>>>(W1l, W1r, W2l, W2r, b1, b2, predW,
                                    emb_user, emb_item,
                                    ug_dst, gi_src, ui_src, ui_dst, ws);
  scan_k1<<<NCHUNK, 256, 0, stream>>>(cnt, chunksum);
  scan2_gemm0<<<NCHUNK + NBI, 256, 0, stream>>>(ws);
  fill_all<<<(ETOT + 255) / 256, 256, 0, stream>>>(ug_src, ug_dst, gi_src, gi_dst,
                                                   ui_src, ui_dst, cur, eidx);
  seg1<<<(NN + 3) / 4, 256, 0, stream>>>(ws);
  gemm1<<<NBU + NBI + NBG, 256, 0, stream>>>(ws);
  seg2<<<(2 * NG + 3) / 4, 256, 0, stream>>>(ws);
  gemm2<<<NBG, 256, 0, stream>>>(ws);
  gemmF<<<dim3(NBG, NBI), 256, 0, stream>>>(ws, predb, (float*)d_out);
}